// Round 4
// baseline (307.417 us; speedup 1.0000x reference)
//
#include <hip/hip_runtime.h>
#include <math.h>

#define NT      256
#define NSYMS   824
#define NPILOT  9

// padded LDS index: +1 element per 16 to break power-of-2 bank strides
#define PADIDX(k) ((k) + ((k) >> 4))

// f32(2*pi/1024): exact value of numpy's float32 ramp constant
#define C32_TWOPI_1024  6.1359233222901821136474609375e-3f

__device__ __forceinline__ float2 cmulf(float2 a, float2 b) {
    return make_float2(a.x * b.x - a.y * b.y, a.x * b.y + a.y * b.x);
}

// ---- in-place radix-4 DIF stage, span L = 4*LM, twiddle scale F = 1024/L ----
// Twiddles from the GLOBAL f32 quadrant table (6 KB, L1-resident on every CU):
// e1 = F*r < 256, e2 = 2F*r < 512, e3 = 3F*r < 768; exact (-i)^q sign/swap
// rotation reconstructs the full circle bit-identically.
template <int LM, int F>
__device__ __forceinline__ void dif_stage(float2* __restrict__ buf,
                                          const float2* __restrict__ Wg,
                                          int i) {
    const int r = i & (LM - 1);
    const int base = ((i & ~(LM - 1)) << 2) | r;
    float2 a = buf[PADIDX(base)];
    float2 b = buf[PADIDX(base + LM)];
    float2 c = buf[PADIDX(base + 2 * LM)];
    float2 d = buf[PADIDX(base + 3 * LM)];
    float2 t0 = make_float2(a.x + c.x, a.y + c.y);
    float2 t1 = make_float2(a.x - c.x, a.y - c.y);
    float2 t2 = make_float2(b.x + d.x, b.y + d.y);
    float2 t3 = make_float2(b.x - d.x, b.y - d.y);
    float2 y0 = make_float2(t0.x + t2.x, t0.y + t2.y);
    float2 y1 = make_float2(t1.x + t3.y, t1.y - t3.x);   // t1 - i*t3
    float2 y2 = make_float2(t0.x - t2.x, t0.y - t2.y);
    float2 y3 = make_float2(t1.x - t3.y, t1.y + t3.x);   // t1 + i*t3
    const int e1 = F * r;                // < 256: no rotation ever needed
    const int e2 = 2 * F * r;            // < 512
    const int e3 = 3 * F * r;            // < 768
    float2 w1 = Wg[e1];
    float2 w2 = Wg[e2 & 255];
    if (e2 & 256) w2 = make_float2(w2.y, -w2.x);          // * (-i), exact
    float2 w3 = Wg[e3 & 255];
    {
        const int q = e3 >> 8;
        if (q == 1)      w3 = make_float2(w3.y, -w3.x);   // * (-i)
        else if (q == 2) w3 = make_float2(-w3.x, -w3.y);  // * (-1)
    }
    buf[PADIDX(base)]          = y0;
    buf[PADIDX(base + LM)]     = cmulf(w1, y1);
    buf[PADIDX(base + 2 * LM)] = cmulf(w2, y2);
    buf[PADIDX(base + 3 * LM)] = cmulf(w3, y3);
}

// ---- one-time table build: identical for every row, so do it ONCE per launch
__global__ void table_init(double2* __restrict__ Tg, float2* __restrict__ Wg) {
    const int t = threadIdx.x;
    double sn, cs;
    sincos((double)t * -6.1359231515425649189e-3, &sn, &cs);  // -2pi/1024
    Tg[t] = make_double2(cs, sn);                 // f64 quadrant (pilot path)
    Wg[t] = make_float2((float)cs, (float)sn);    // f32 quadrant (FFT path)
}

// LDS: u_s 4096 + buf 8704 + pr2 144 + mn_s 8 = 12952 -> 13312 granule.
// Wave-capped at 8 blocks/CU (32 waves) -> ~100% theoretical occupancy.
__global__ __launch_bounds__(NT, 8) void ofdm_kernel(const float* __restrict__ in,
                                                     float* __restrict__ out,
                                                     const double2* __restrict__ Tg,
                                                     const float2* __restrict__ Wg) {
    __shared__ double2 u_s[NT];       // radix-4 folded input for pilot DFT
    __shared__ float2  buf[1088];     // single in-place FFT buffer (padded)
    __shared__ double2 pr2[NPILOT];   // reduced pilot sums (pre-finalize)
    __shared__ double  mn_s;          // broadcast wrapped-diff mean

    const int row = blockIdx.x;       // 0..16383
    const int tid = threadIdx.x;

    // ---- load 1024 complex samples at complex offset 128 (CP/2) ----
    const float2* rin2 = (const float2*)(in + (size_t)row * 2560) + 128;
    float2 v0 = rin2[tid];
    float2 v1 = rin2[tid + 256];
    float2 v2 = rin2[tid + 512];
    float2 v3 = rin2[tid + 768];

    // ---- pilot fold (f64): u_t = x_t + i*x_{t+256} - x_{t+512} - i*x_{t+768}
    // valid because pilot FFT bins K = (jj+512)&1023 satisfy K mod 4 == 3,
    // so w^{256*K*delta} = i^delta.
    double ux = ((double)v0.x - (double)v2.x) - ((double)v1.y - (double)v3.y);
    double uy = ((double)v0.y - (double)v2.y) + ((double)v1.x - (double)v3.x);

    // ---- FFT stage 1 (span 1024) IN REGISTERS: thread t already holds its
    // butterfly inputs {t, t+256, t+512, t+768} = v0..v3. Twiddles straight
    // from the global table (same values the LDS path used -> bit-identical).
    {
        const int e2 = 2 * tid, e3 = 3 * tid;      // e1 = tid < 256
        float2 w1 = Wg[tid];
        float2 w2 = Wg[e2 & 255];
        if (e2 & 256) w2 = make_float2(w2.y, -w2.x);
        float2 w3 = Wg[e3 & 255];
        {
            const int q = e3 >> 8;
            if (q == 1)      w3 = make_float2(w3.y, -w3.x);
            else if (q == 2) w3 = make_float2(-w3.x, -w3.y);
        }
        float2 t0 = make_float2(v0.x + v2.x, v0.y + v2.y);
        float2 t1 = make_float2(v0.x - v2.x, v0.y - v2.y);
        float2 t2 = make_float2(v1.x + v3.x, v1.y + v3.y);
        float2 t3 = make_float2(v1.x - v3.x, v1.y - v3.y);
        float2 y0 = make_float2(t0.x + t2.x, t0.y + t2.y);
        float2 y1 = make_float2(t1.x + t3.y, t1.y - t3.x);   // t1 - i*t3
        float2 y2 = make_float2(t0.x - t2.x, t0.y - t2.y);
        float2 y3 = make_float2(t1.x - t3.y, t1.y + t3.x);   // t1 + i*t3
        buf[PADIDX(tid)]       = y0;
        buf[PADIDX(tid + 256)] = cmulf(w1, y1);
        buf[PADIDX(tid + 512)] = cmulf(w2, y2);
        buf[PADIDX(tid + 768)] = cmulf(w3, y3);
    }
    u_s[tid] = make_double2(ux, uy);
    __syncthreads();                               // sync0

    // ---- pilot DFT, folded 256->128: all pilot bins K satisfy K mod 8 in {3,7},
    // so w^{128K} = sigma*(sqrt2/2)*(1+i) exactly. f64 twiddles read from the
    // GLOBAL quadrant table (4 KB, L1-hot; was the main LDS bank-conflict source).
    if (tid < 16 * NPILOT) {
        const int p  = tid >> 4;
        const int g  = tid & 15;
        const int jj = 95 + 100 * p;
        const int K  = (jj + 512) & 1023;     // rolled FFT bin
        const double sc = (p & 1) ? -0.70710678118654752440
                                  :  0.70710678118654752440;
        int idx = (K * g) & 1023;
        const int step = (K * 16) & 1023;
        double2 acc = make_double2(0.0, 0.0);
        #pragma unroll
        for (int m = 0; m < 8; m++) {
            const int s = g + 16 * m;         // s < 128
            double2 u0 = u_s[s];              // broadcast across 16-lane groups
            double2 u1 = u_s[s + 128];
            // u' = u0 + sc*(1+i)*u1 ; (1+i)(a+ib) = (a-b) + i(a+b)
            double upx = u0.x + sc * (u1.x - u1.y);
            double upy = u0.y + sc * (u1.x + u1.y);
            double2 w  = Tg[idx & 255];       // global, L1-resident
            // exact quadrant rotation by (-i)^(idx>>8): sign/swap only
            const int q = idx >> 8;
            double wx = w.x, wy = w.y;
            if (q & 1) { double t = wx; wx = wy; wy = -t; }
            if (q & 2) { wx = -wx; wy = -wy; }
            acc.x += wx * upx - wy * upy;
            acc.y += wx * upy + wy * upx;
            idx = (idx + step) & 1023;
        }
        // butterfly reduce across the 16-lane pilot group
        #pragma unroll
        for (int off = 1; off < 16; off <<= 1) {
            acc.x += __shfl_xor(acc.x, off, 64);
            acc.y += __shfl_xor(acc.y, off, 64);
        }
        if (g == 0) pr2[p] = acc;             // raw sum; finalize on wave 3 later
    }
    // ---- FFT stage 2 (span 256) in the same phase ----
    dif_stage<64, 4>(buf, Wg, tid);
    __syncthreads();                               // sync1

    dif_stage<16, 16>(buf, Wg, tid);               // span 64
    // ---- pilot finalize + wrapped-diff mean, entirely on wave 3 ----
    if (tid >= 192) {
        const int p  = tid - 192;
        const int pc = (p < 8) ? p : 8;       // clamp: lanes 9..63 duplicate pilot 8
        double2 acc = pr2[pc];
        const int jj = 95 + 100 * pc;
        // bit-exact emulation of numpy's complex64 ramp (round-4 formula)
        float th32 = (float)(128 * jj) * C32_TWOPI_1024;
        double sn, cs;
        sincos((double)th32, &sn, &cs);
        double csf = (double)(float)cs;
        double snf = (double)(float)sn;
        double re = acc.x * csf - acc.y * snf;
        double im = acc.x * snf + acc.y * csf;
        double a  = atan2(im, re);
        // wrapped diff: lane p takes a_{p+1} - a_p (valid for p<8), then 8-lane sum
        double an = __shfl_down(a, 1, 64);    // all 64 lanes active
        double d  = an - a;
        if (d > 3.14159265358979323846)       d -= 6.28318530717958647693;
        else if (d < -3.14159265358979323846) d += 6.28318530717958647693;
        if (p >= 8) d = 0.0;
        d += __shfl_xor(d, 1, 64);            // partners of lanes 0-7 stay in 0-7
        d += __shfl_xor(d, 2, 64);
        d += __shfl_xor(d, 4, 64);
        if (p == 0) mn_s = d * 0.125;
    }
    __syncthreads();                               // sync2

    dif_stage<4, 64>(buf, Wg, tid);                // span 16
    __syncthreads();                               // sync3

    // ---- fused final stage (span 4, unit twiddles) + correction + gather ----
    // After 5 DIF stages output is base-4 digit-reversed: slot n holds X[rev(n)].
    // Thread t butterflies slots {4t..4t+3} (contiguous, same padded 16-group),
    // producing bins {R, R+256, R+512, R+768} with R = rev4(t). After the ^512
    // roll these are the four jj == R (mod 256). Inverse data map: valid iff
    // 96 <= jj <= 927 and (jj-95)%100 != 0; d = jj - 96 - (jj-96)/100.
    {
        const double mn001 = mn_s * 0.01;     // (mn*0.01)*jj == mn*0.01*jj (assoc)
        const int pb = PADIDX(4 * tid);       // 4t..4t+3 never cross a pad group
        float2 a = buf[pb];
        float2 b = buf[pb + 1];
        float2 c = buf[pb + 2];
        float2 d = buf[pb + 3];
        float2 t0 = make_float2(a.x + c.x, a.y + c.y);
        float2 t1 = make_float2(a.x - c.x, a.y - c.y);
        float2 t2 = make_float2(b.x + d.x, b.y + d.y);
        float2 t3 = make_float2(b.x - d.x, b.y - d.y);
        float2 y0 = make_float2(t0.x + t2.x, t0.y + t2.y);  // bin R      -> jj = R+512
        float2 y1 = make_float2(t1.x + t3.y, t1.y - t3.x);  // bin R+256  -> jj = R+768
        float2 y2 = make_float2(t0.x - t2.x, t0.y - t2.y);  // bin R+512  -> jj = R
        float2 y3 = make_float2(t1.x - t3.y, t1.y + t3.x);  // bin R+768  -> jj = R+256

        const int R = ((tid & 3) << 6) | (((tid >> 2) & 3) << 4) |
                      (((tid >> 4) & 3) << 2) | ((tid >> 6) & 3);

        float2* rout = (float2*)(out + (size_t)row * (2 * NSYMS));
        float2 ys[4] = { y2, y3, y0, y1 };    // ordered by jj = R, R+256, R+512, R+768
        #pragma unroll
        for (int k = 0; k < 4; k++) {
            const int jj = R + 256 * k;
            if (jj >= 96 && jj <= 927 && ((jj - 95) % 100) != 0) {
                const int dd = jj - 96 - (jj - 96) / 100;
                float2 z = ys[k];
                float th32 = (float)(128 * jj) * C32_TWOPI_1024;
                float ph = th32 - (float)(mn001 * (double)jj);
                float sn, cs;
                __sincosf(ph, &sn, &cs);
                rout[dd] = make_float2(z.x * cs - z.y * sn,
                                       z.x * sn + z.y * cs);
            }
        }
    }
}

extern "C" void kernel_launch(void* const* d_in, const int* in_sizes, int n_in,
                              void* d_out, int out_size, void* d_ws, size_t ws_size,
                              hipStream_t stream) {
    const float* in = (const float*)d_in[0];
    float* out = (float*)d_out;
    double2* Tg = (double2*)d_ws;                       // 256 * 16 B = 4096 B
    float2*  Wg = (float2*)((char*)d_ws + 4096);        // 256 *  8 B = 2048 B
    table_init<<<dim3(1), dim3(256), 0, stream>>>(Tg, Wg);
    ofdm_kernel<<<dim3(16 * 1024), dim3(NT), 0, stream>>>(in, out, Tg, Wg);
}

// Round 5
// 268.519 us; speedup vs baseline: 1.1449x; 1.1449x over previous
//
#include <hip/hip_runtime.h>
#include <math.h>

#define NT      256
#define NSYMS   824
#define NPILOT  9

// padded LDS index: +1 element per 16 to break power-of-2 bank strides
#define PADIDX(k) ((k) + ((k) >> 4))

// f32(2*pi/1024): exact value of numpy's float32 ramp constant
#define C32_TWOPI_1024  6.1359233222901821136474609375e-3f

__device__ __forceinline__ float2 cmulf(float2 a, float2 b) {
    return make_float2(a.x * b.x - a.y * b.y, a.x * b.y + a.y * b.x);
}

// ---- in-place radix-4 DIF stage, span L = 4*LM, twiddle scale F = 1024/L ----
// butterfly i: slots base + {0,LM,2LM,3LM}, base = (i/LM)*4LM + (i%LM).
// Twiddles from the LDS f32 quadrant (global-table gathers regressed 23%:
// 64 divergent addrs/wave serialize in L1 and the vmcnt stall sits between
// barriers where TLP can't hide it — round-4 lesson).
// e1 = F*r < 256, e2 = 2F*r < 512, e3 = 3F*r < 768; exact (-i)^q sign/swap.
template <int LM, int F>
__device__ __forceinline__ void dif_stage(float2* __restrict__ buf,
                                          const float2* __restrict__ W256,
                                          int i) {
    const int r = i & (LM - 1);
    const int base = ((i & ~(LM - 1)) << 2) | r;
    float2 a = buf[PADIDX(base)];
    float2 b = buf[PADIDX(base + LM)];
    float2 c = buf[PADIDX(base + 2 * LM)];
    float2 d = buf[PADIDX(base + 3 * LM)];
    float2 t0 = make_float2(a.x + c.x, a.y + c.y);
    float2 t1 = make_float2(a.x - c.x, a.y - c.y);
    float2 t2 = make_float2(b.x + d.x, b.y + d.y);
    float2 t3 = make_float2(b.x - d.x, b.y - d.y);
    float2 y0 = make_float2(t0.x + t2.x, t0.y + t2.y);
    float2 y1 = make_float2(t1.x + t3.y, t1.y - t3.x);   // t1 - i*t3
    float2 y2 = make_float2(t0.x - t2.x, t0.y - t2.y);
    float2 y3 = make_float2(t1.x - t3.y, t1.y + t3.x);   // t1 + i*t3
    const int e1 = F * r;                // < 256: no rotation ever needed
    const int e2 = 2 * F * r;            // < 512
    const int e3 = 3 * F * r;            // < 768
    float2 w1 = W256[PADIDX(e1)];
    float2 w2 = W256[PADIDX(e2 & 255)];
    if (e2 & 256) w2 = make_float2(w2.y, -w2.x);          // * (-i), exact
    float2 w3 = W256[PADIDX(e3 & 255)];
    {
        const int q = e3 >> 8;
        if (q == 1)      w3 = make_float2(w3.y, -w3.x);   // * (-i)
        else if (q == 2) w3 = make_float2(-w3.x, -w3.y);  // * (-1)
    }
    buf[PADIDX(base)]          = y0;
    buf[PADIDX(base + LM)]     = cmulf(w1, y1);
    buf[PADIDX(base + 2 * LM)] = cmulf(w2, y2);
    buf[PADIDX(base + 3 * LM)] = cmulf(w3, y3);
}

// ---- one-time table build: identical for every row, so do it ONCE per launch
__global__ void table_init(double2* __restrict__ Tg, float2* __restrict__ Wg) {
    const int t = threadIdx.x;
    double sn, cs;
    sincos((double)t * -6.1359231515425649189e-3, &sn, &cs);  // -2pi/1024
    Tg[t] = make_double2(cs, sn);                 // f64 quadrant (pilot path)
    Wg[t] = make_float2((float)cs, (float)sn);    // f32 quadrant (FFT path)
}

// LDS: T256 4096 + u_s 4096 + buf 8704 + W256 2176 + pr2 144 + mn_s 8 = 19224
// -> 19456 granule -> 8 blocks/CU = 32 waves = 100% occupancy.
__global__ __launch_bounds__(NT, 8) void ofdm_kernel(const float* __restrict__ in,
                                                     float* __restrict__ out,
                                                     const double2* __restrict__ Tg,
                                                     const float2* __restrict__ Wg) {
    __shared__ double2 T256[256];     // f64 twiddle quadrant (pilot path)
    __shared__ double2 u_s[NT];       // radix-4 folded input for pilot DFT
    __shared__ float2  buf[1088];     // single in-place FFT buffer (padded)
    __shared__ float2  W256[272];     // f32 twiddle quadrant (padded)
    __shared__ double2 pr2[NPILOT];   // reduced pilot sums (pre-finalize)
    __shared__ double  mn_s;          // broadcast wrapped-diff mean

    const int row = blockIdx.x;       // 0..16383
    const int tid = threadIdx.x;

    // ---- load 1024 complex samples at complex offset 128 (CP/2) ----
    const float2* rin2 = (const float2*)(in + (size_t)row * 2560) + 128;
    float2 v0 = rin2[tid];
    float2 v1 = rin2[tid + 256];
    float2 v2 = rin2[tid + 512];
    float2 v3 = rin2[tid + 768];

    // ---- stage twiddle tables into LDS (coalesced, L2-broadcast) ----
    T256[tid] = Tg[tid];
    W256[PADIDX(tid)] = Wg[tid];

    // ---- pilot fold (f64): u_t = x_t + i*x_{t+256} - x_{t+512} - i*x_{t+768}
    // valid because pilot FFT bins K = (jj+512)&1023 satisfy K mod 4 == 3,
    // so w^{256*K*delta} = i^delta.
    double ux = ((double)v0.x - (double)v2.x) - ((double)v1.y - (double)v3.y);
    double uy = ((double)v0.y - (double)v2.y) + ((double)v1.x - (double)v3.x);

    // ---- FFT stage 1 (span 1024) IN REGISTERS: thread t already holds its
    // butterfly inputs {t, t+256, t+512, t+768} = v0..v3. Twiddles read ONCE
    // from the global table (contiguous ranges, issued before the first
    // barrier where the pilot fold hides the latency) -> bit-identical values.
    {
        const int e2 = 2 * tid, e3 = 3 * tid;      // e1 = tid < 256
        float2 w1 = Wg[tid];
        float2 w2 = Wg[e2 & 255];
        if (e2 & 256) w2 = make_float2(w2.y, -w2.x);
        float2 w3 = Wg[e3 & 255];
        {
            const int q = e3 >> 8;
            if (q == 1)      w3 = make_float2(w3.y, -w3.x);
            else if (q == 2) w3 = make_float2(-w3.x, -w3.y);
        }
        float2 t0 = make_float2(v0.x + v2.x, v0.y + v2.y);
        float2 t1 = make_float2(v0.x - v2.x, v0.y - v2.y);
        float2 t2 = make_float2(v1.x + v3.x, v1.y + v3.y);
        float2 t3 = make_float2(v1.x - v3.x, v1.y - v3.y);
        float2 y0 = make_float2(t0.x + t2.x, t0.y + t2.y);
        float2 y1 = make_float2(t1.x + t3.y, t1.y - t3.x);   // t1 - i*t3
        float2 y2 = make_float2(t0.x - t2.x, t0.y - t2.y);
        float2 y3 = make_float2(t1.x - t3.y, t1.y + t3.x);   // t1 + i*t3
        buf[PADIDX(tid)]       = y0;
        buf[PADIDX(tid + 256)] = cmulf(w1, y1);
        buf[PADIDX(tid + 512)] = cmulf(w2, y2);
        buf[PADIDX(tid + 768)] = cmulf(w3, y3);
    }
    u_s[tid] = make_double2(ux, uy);
    __syncthreads();                               // sync0

    // ---- pilot DFT, folded 256->128: all pilot bins K satisfy K mod 8 in {3,7},
    // so w^{128K} = sigma*(sqrt2/2)*(1+i) exactly. f64 twiddles from LDS T256.
    if (tid < 16 * NPILOT) {
        const int p  = tid >> 4;
        const int g  = tid & 15;
        const int jj = 95 + 100 * p;
        const int K  = (jj + 512) & 1023;     // rolled FFT bin
        const double sc = (p & 1) ? -0.70710678118654752440
                                  :  0.70710678118654752440;
        int idx = (K * g) & 1023;
        const int step = (K * 16) & 1023;
        double2 acc = make_double2(0.0, 0.0);
        #pragma unroll
        for (int m = 0; m < 8; m++) {
            const int s = g + 16 * m;         // s < 128
            double2 u0 = u_s[s];              // adjacent lanes -> consecutive
            double2 u1 = u_s[s + 128];
            // u' = u0 + sc*(1+i)*u1 ; (1+i)(a+ib) = (a-b) + i(a+b)
            double upx = u0.x + sc * (u1.x - u1.y);
            double upy = u0.y + sc * (u1.x + u1.y);
            double2 w  = T256[idx & 255];
            // exact quadrant rotation by (-i)^(idx>>8): sign/swap only
            const int q = idx >> 8;
            double wx = w.x, wy = w.y;
            if (q & 1) { double t = wx; wx = wy; wy = -t; }
            if (q & 2) { wx = -wx; wy = -wy; }
            acc.x += wx * upx - wy * upy;
            acc.y += wx * upy + wy * upx;
            idx = (idx + step) & 1023;
        }
        // butterfly reduce across the 16-lane pilot group
        #pragma unroll
        for (int off = 1; off < 16; off <<= 1) {
            acc.x += __shfl_xor(acc.x, off, 64);
            acc.y += __shfl_xor(acc.y, off, 64);
        }
        if (g == 0) pr2[p] = acc;             // raw sum; finalize on wave 3 later
    }
    // ---- FFT stage 2 (span 256) in the same phase ----
    dif_stage<64, 4>(buf, W256, tid);
    __syncthreads();                               // sync1

    dif_stage<16, 16>(buf, W256, tid);             // span 64
    // ---- pilot finalize + wrapped-diff mean, entirely on wave 3 ----
    if (tid >= 192) {
        const int p  = tid - 192;
        const int pc = (p < 8) ? p : 8;       // clamp: lanes 9..63 duplicate pilot 8
        double2 acc = pr2[pc];
        const int jj = 95 + 100 * pc;
        // bit-exact emulation of numpy's complex64 ramp (round-4 formula)
        float th32 = (float)(128 * jj) * C32_TWOPI_1024;
        double sn, cs;
        sincos((double)th32, &sn, &cs);
        double csf = (double)(float)cs;
        double snf = (double)(float)sn;
        double re = acc.x * csf - acc.y * snf;
        double im = acc.x * snf + acc.y * csf;
        double a  = atan2(im, re);
        // wrapped diff: lane p takes a_{p+1} - a_p (valid for p<8), then 8-lane sum
        double an = __shfl_down(a, 1, 64);    // all 64 lanes active
        double d  = an - a;
        if (d > 3.14159265358979323846)       d -= 6.28318530717958647693;
        else if (d < -3.14159265358979323846) d += 6.28318530717958647693;
        if (p >= 8) d = 0.0;
        d += __shfl_xor(d, 1, 64);            // partners of lanes 0-7 stay in 0-7
        d += __shfl_xor(d, 2, 64);
        d += __shfl_xor(d, 4, 64);
        if (p == 0) mn_s = d * 0.125;
    }
    __syncthreads();                               // sync2

    dif_stage<4, 64>(buf, W256, tid);              // span 16
    __syncthreads();                               // sync3

    // ---- fused final stage (span 4, unit twiddles) + correction + gather ----
    // After 5 DIF stages output is base-4 digit-reversed: slot n holds X[rev(n)].
    // Thread t butterflies slots {4t..4t+3} (contiguous, same padded 16-group),
    // producing bins {R, R+256, R+512, R+768} with R = rev4(t). After the ^512
    // roll these are the four jj == R (mod 256). Inverse data map: valid iff
    // 96 <= jj <= 927 and (jj-95)%100 != 0; d = jj - 96 - (jj-96)/100.
    {
        const double mn001 = mn_s * 0.01;     // (mn*0.01)*jj == mn*0.01*jj (assoc)
        const int pb = PADIDX(4 * tid);       // 4t..4t+3 never cross a pad group
        float2 a = buf[pb];
        float2 b = buf[pb + 1];
        float2 c = buf[pb + 2];
        float2 d = buf[pb + 3];
        float2 t0 = make_float2(a.x + c.x, a.y + c.y);
        float2 t1 = make_float2(a.x - c.x, a.y - c.y);
        float2 t2 = make_float2(b.x + d.x, b.y + d.y);
        float2 t3 = make_float2(b.x - d.x, b.y - d.y);
        float2 y0 = make_float2(t0.x + t2.x, t0.y + t2.y);  // bin R      -> jj = R+512
        float2 y1 = make_float2(t1.x + t3.y, t1.y - t3.x);  // bin R+256  -> jj = R+768
        float2 y2 = make_float2(t0.x - t2.x, t0.y - t2.y);  // bin R+512  -> jj = R
        float2 y3 = make_float2(t1.x - t3.y, t1.y + t3.x);  // bin R+768  -> jj = R+256

        const int R = ((tid & 3) << 6) | (((tid >> 2) & 3) << 4) |
                      (((tid >> 4) & 3) << 2) | ((tid >> 6) & 3);

        float2* rout = (float2*)(out + (size_t)row * (2 * NSYMS));
        float2 ys[4] = { y2, y3, y0, y1 };    // ordered by jj = R, R+256, R+512, R+768
        #pragma unroll
        for (int k = 0; k < 4; k++) {
            const int jj = R + 256 * k;
            if (jj >= 96 && jj <= 927 && ((jj - 95) % 100) != 0) {
                const int dd = jj - 96 - (jj - 96) / 100;
                float2 z = ys[k];
                float th32 = (float)(128 * jj) * C32_TWOPI_1024;
                float ph = th32 - (float)(mn001 * (double)jj);
                float sn, cs;
                __sincosf(ph, &sn, &cs);
                rout[dd] = make_float2(z.x * cs - z.y * sn,
                                       z.x * sn + z.y * cs);
            }
        }
    }
}

extern "C" void kernel_launch(void* const* d_in, const int* in_sizes, int n_in,
                              void* d_out, int out_size, void* d_ws, size_t ws_size,
                              hipStream_t stream) {
    const float* in = (const float*)d_in[0];
    float* out = (float*)d_out;
    double2* Tg = (double2*)d_ws;                       // 256 * 16 B = 4096 B
    float2*  Wg = (float2*)((char*)d_ws + 4096);        // 256 *  8 B = 2048 B
    table_init<<<dim3(1), dim3(256), 0, stream>>>(Tg, Wg);
    ofdm_kernel<<<dim3(16 * 1024), dim3(NT), 0, stream>>>(in, out, Tg, Wg);
}